// Round 1
// baseline (403.287 us; speedup 1.0000x reference)
//
#include <hip/hip_runtime.h>
#include <math.h>

#define BATCH 32
#define CH 256
#define HW 4096
#define KSEL 8           // NUM_FEATURES / NUM_GROUPS = 8
#define EPSV 1e-5f

// ---------------- K1: per-(b,c) spatial sums + inverse norms ----------------
__global__ __launch_bounds__(256) void stats_kernel(const float* __restrict__ x,
                                                    float* __restrict__ s,
                                                    float* __restrict__ sq,
                                                    float* __restrict__ invn) {
    int bc = blockIdx.x;                       // 0..8191 = b*256+c
    const float4* p4 = (const float4*)(x + (size_t)bc * HW);
    int t = threadIdx.x;                       // 256 threads
    float sum = 0.f, ssq = 0.f;
#pragma unroll
    for (int i = 0; i < 4; ++i) {
        float4 v = p4[t + 256 * i];
        sum += v.x + v.y + v.z + v.w;
        ssq += v.x * v.x + v.y * v.y + v.z * v.z + v.w * v.w;
    }
    for (int off = 32; off; off >>= 1) {
        sum += __shfl_down(sum, off);
        ssq += __shfl_down(ssq, off);
    }
    __shared__ float ls[4], lq[4];
    int wid = t >> 6, lane = t & 63;
    if (lane == 0) { ls[wid] = sum; lq[wid] = ssq; }
    __syncthreads();
    if (t == 0) {
        float S = ls[0] + ls[1] + ls[2] + ls[3];
        float Q = lq[0] + lq[1] + lq[2] + lq[3];
        s[bc] = S;
        sq[bc] = Q;
        invn[bc] = 1.0f / fmaxf(sqrtf(Q), 1e-12f);
    }
}

// ---------------- K2: per-batch Gram matrix S_b = X_b * X_b^T ----------------
#define TS 64
#define KT 32
#define LDP 66            // padded row (floats); float2 reads -> <=2-way bank alias (free)

__global__ __launch_bounds__(256) void gram_kernel(const float* __restrict__ x,
                                                   float* __restrict__ S) {
    int tj = blockIdx.x;        // col tile 0..3
    int ti = blockIdx.y;        // row tile 0..3
    int b  = blockIdx.z;        // batch
    const float* xb = x + (size_t)b * CH * HW;

    __shared__ float As[TS][LDP];
    __shared__ float Bs[TS][LDP];

    int t  = threadIdx.x;
    int tx = t & 15, ty = t >> 4;
    int r0 = ti * TS, c0 = tj * TS;

    // staging map: 64 rows x 32 cols per tile = 512 float4; thread t does rows (t>>3) and (t>>3)+32
    int srow = t >> 3;          // 0..31
    int sc4  = t & 7;           // 0..7 -> float col sc4*4

    float acc[4][4] = {};

    for (int kc = 0; kc < HW / KT; ++kc) {
        int k0 = kc * KT;
        // global loads (registers) before the barrier
        float4 a0 = *(const float4*)&xb[(size_t)(r0 + srow)      * HW + k0 + sc4 * 4];
        float4 a1 = *(const float4*)&xb[(size_t)(r0 + srow + 32) * HW + k0 + sc4 * 4];
        float4 b0 = *(const float4*)&xb[(size_t)(c0 + srow)      * HW + k0 + sc4 * 4];
        float4 b1 = *(const float4*)&xb[(size_t)(c0 + srow + 32) * HW + k0 + sc4 * 4];
        __syncthreads();   // previous chunk's compute done
        {
            float2* dA0 = (float2*)&As[srow][sc4 * 4];
            dA0[0] = make_float2(a0.x, a0.y); dA0[1] = make_float2(a0.z, a0.w);
            float2* dA1 = (float2*)&As[srow + 32][sc4 * 4];
            dA1[0] = make_float2(a1.x, a1.y); dA1[1] = make_float2(a1.z, a1.w);
            float2* dB0 = (float2*)&Bs[srow][sc4 * 4];
            dB0[0] = make_float2(b0.x, b0.y); dB0[1] = make_float2(b0.z, b0.w);
            float2* dB1 = (float2*)&Bs[srow + 32][sc4 * 4];
            dB1[0] = make_float2(b1.x, b1.y); dB1[1] = make_float2(b1.z, b1.w);
        }
        __syncthreads();   // tiles ready
#pragma unroll
        for (int k = 0; k < KT; k += 2) {
            float2 av[4], bv[4];
#pragma unroll
            for (int i = 0; i < 4; ++i) av[i] = *(const float2*)&As[ty + 16 * i][k];
#pragma unroll
            for (int j = 0; j < 4; ++j) bv[j] = *(const float2*)&Bs[tx + 16 * j][k];
#pragma unroll
            for (int i = 0; i < 4; ++i)
#pragma unroll
                for (int j = 0; j < 4; ++j) {
                    acc[i][j] += av[i].x * bv[j].x;
                    acc[i][j] += av[i].y * bv[j].y;
                }
        }
    }

    float* Sb = S + (size_t)b * CH * CH;
#pragma unroll
    for (int i = 0; i < 4; ++i)
#pragma unroll
        for (int j = 0; j < 4; ++j)
            Sb[(size_t)(r0 + ty + 16 * i) * CH + (c0 + tx + 16 * j)] = acc[i][j];
}

// ---------------- K3a: cos column + top-8 smallest |cos| ----------------
__global__ __launch_bounds__(256) void topk_kernel(const float* __restrict__ S,
                                                   const float* __restrict__ invn,
                                                   int* __restrict__ idx) {
    int c = blockIdx.x;        // column
    int d = threadIdx.x;       // row
    float v = 0.f;
    for (int b = 0; b < BATCH; ++b) {
        v += S[(size_t)b * CH * CH + (size_t)d * CH + c] * invn[b * CH + d] * invn[b * CH + c];
    }
    v = fabsf(v * (1.0f / BATCH));

    __shared__ unsigned long long keys[CH];
    __shared__ unsigned long long wmin[4];
    __shared__ unsigned long long bmin;

    keys[d] = ((unsigned long long)__float_as_uint(v) << 32) | (unsigned)d;
    __syncthreads();

    for (int i = 0; i < KSEL; ++i) {
        unsigned long long k = keys[d];
        for (int off = 32; off; off >>= 1) {
            unsigned long long o = __shfl_down(k, off);
            k = (o < k) ? o : k;
        }
        if ((d & 63) == 0) wmin[d >> 6] = k;
        __syncthreads();
        if (d == 0) {
            unsigned long long m = wmin[0];
            if (wmin[1] < m) m = wmin[1];
            if (wmin[2] < m) m = wmin[2];
            if (wmin[3] < m) m = wmin[3];
            bmin = m;
            idx[c * KSEL + i] = (int)(m & 0xffffffffu);
        }
        __syncthreads();
        int sel = (int)(bmin & 0xffffffffu);
        if (d == sel) keys[d] = 0xffffffffffffffffULL;
        __syncthreads();
    }
}

// ---------------- K3b: gathered group statistics ----------------
__global__ __launch_bounds__(256) void groupstat_kernel(const float* __restrict__ s,
                                                        const float* __restrict__ sq,
                                                        const int* __restrict__ idx,
                                                        float* __restrict__ mean,
                                                        float* __restrict__ inv) {
    int b = blockIdx.x, c = threadIdx.x;
    float gs = s[b * CH + c], gq = sq[b * CH + c];
#pragma unroll
    for (int i = 1; i < KSEL; ++i) {
        int d = idx[c * KSEL + i];
        gs += s[b * CH + d];
        gq += sq[b * CH + d];
    }
    const float Ninv = 1.0f / (float)(KSEL * HW);
    float m = gs * Ninv;
    float var = gq * Ninv - m * m;
    mean[b * CH + c] = m;
    inv[b * CH + c]  = rsqrtf(var + EPSV);
}

// ---------------- K4: normalize ----------------
__global__ __launch_bounds__(256) void norm_kernel(const float* __restrict__ x,
                                                   const float* __restrict__ mean,
                                                   const float* __restrict__ inv,
                                                   const float* __restrict__ gamma,
                                                   const float* __restrict__ beta,
                                                   float* __restrict__ out) {
    int i = blockIdx.x * 256 + threadIdx.x;   // float4 index, exact grid
    int bc = i >> 10;                          // 1024 float4 per (b,c)
    int c  = bc & (CH - 1);
    float m = mean[bc], v = inv[bc];
    float g  = gamma[c] * v;
    float bt = beta[c] - m * g;
    float4 xv = ((const float4*)x)[i];
    float4 o;
    o.x = xv.x * g + bt;
    o.y = xv.y * g + bt;
    o.z = xv.z * g + bt;
    o.w = xv.w * g + bt;
    ((float4*)out)[i] = o;
}

extern "C" void kernel_launch(void* const* d_in, const int* in_sizes, int n_in,
                              void* d_out, int out_size, void* d_ws, size_t ws_size,
                              hipStream_t stream) {
    const float* x     = (const float*)d_in[0];
    const float* gamma = (const float*)d_in[1];
    const float* beta  = (const float*)d_in[2];
    float* out = (float*)d_out;

    float* ws   = (float*)d_ws;
    float* S    = ws;                                   // 32*256*256 = 2,097,152 floats
    float* s    = S + (size_t)BATCH * CH * CH;          // 8192
    float* sq   = s + BATCH * CH;                       // 8192
    float* invn = sq + BATCH * CH;                      // 8192
    float* mean = invn + BATCH * CH;                    // 8192
    float* inv  = mean + BATCH * CH;                    // 8192
    int*   idx  = (int*)(inv + BATCH * CH);             // 256*8 ints

    stats_kernel<<<BATCH * CH, 256, 0, stream>>>(x, s, sq, invn);
    gram_kernel<<<dim3(4, 4, BATCH), 256, 0, stream>>>(x, S);
    topk_kernel<<<CH, 256, 0, stream>>>(S, invn, idx);
    groupstat_kernel<<<BATCH, 256, 0, stream>>>(s, sq, idx, mean, inv);
    norm_kernel<<<(BATCH * CH * HW / 4) / 256, 256, 0, stream>>>(x, mean, inv, gamma, beta, out);
}

// Round 2
// 223.138 us; speedup vs baseline: 1.8073x; 1.8073x over previous
//
#include <hip/hip_runtime.h>
#include <math.h>

#define BATCH 32
#define CH 256
#define HW 4096
#define KSEL 8
#define EPSV 1e-5f

typedef __attribute__((ext_vector_type(8))) short short8;
typedef __attribute__((ext_vector_type(4))) float f32x4;

__device__ __forceinline__ unsigned short f2bf(float f) {
    unsigned u = __float_as_uint(f);
    unsigned r = u + 0x7fffu + ((u >> 16) & 1u);   // RNE
    return (unsigned short)(r >> 16);
}
__device__ __forceinline__ float bf2f(unsigned short h) {
    return __uint_as_float(((unsigned)h) << 16);
}

// ---------------- K1: per-(b,c) spatial sums + inverse norms ----------------
__global__ __launch_bounds__(256) void stats_kernel(const float* __restrict__ x,
                                                    float* __restrict__ s,
                                                    float* __restrict__ sq,
                                                    float* __restrict__ invn) {
    int bc = blockIdx.x;
    const float4* p4 = (const float4*)(x + (size_t)bc * HW);
    int t = threadIdx.x;
    float sum = 0.f, ssq = 0.f;
#pragma unroll
    for (int i = 0; i < 4; ++i) {
        float4 v = p4[t + 256 * i];
        sum += v.x + v.y + v.z + v.w;
        ssq += v.x * v.x + v.y * v.y + v.z * v.z + v.w * v.w;
    }
    for (int off = 32; off; off >>= 1) {
        sum += __shfl_down(sum, off);
        ssq += __shfl_down(ssq, off);
    }
    __shared__ float ls[4], lq[4];
    int wid = t >> 6, lane = t & 63;
    if (lane == 0) { ls[wid] = sum; lq[wid] = ssq; }
    __syncthreads();
    if (t == 0) {
        float S = ls[0] + ls[1] + ls[2] + ls[3];
        float Q = lq[0] + lq[1] + lq[2] + lq[3];
        s[bc] = S;
        sq[bc] = Q;
        invn[bc] = 1.0f / fmaxf(sqrtf(Q), 1e-12f);
    }
}

// ------------- K2: MFMA Gram partial: C1 = H*H^T + H*(2L)^T ---------------
// 128x128 tile, 4 waves of 64x64, mfma_f32_16x16x32_bf16, K_TILE=64 in LDS,
// XOR-swizzled rows (row stride 128B would be 32-way bank conflict).
__global__ __launch_bounds__(256) void gram_mfma(const float* __restrict__ x,
                                                 float* __restrict__ C1,   // [P][B][256][256]
                                                 int P) {
    int bj = blockIdx.x, bi = blockIdx.y;
    int z = blockIdx.z;
    int b = z / P, p = z - b * P;
    const float* xb = x + (size_t)b * CH * HW;
    int klen = HW / P;
    int kbase = p * klen;

    __shared__ unsigned short Ah[128 * 64];
    __shared__ unsigned short Bh[128 * 64];
    __shared__ unsigned short Bl[128 * 64];

    int t = threadIdx.x;
    int lane = t & 63, w = t >> 6;
    int wr = (w >> 1) * 64, wc = (w & 1) * 64;
    int fr = lane & 15;          // frag row/col within 16
    int fg = lane >> 4;          // k-group 0..3

    // staging map: float4 f = t + 256*i ; row = (t>>4)+16*i ; col4 = t&15
    int srow = t >> 4;
    int c4 = t & 15;
    int g = c4 >> 1;             // 16B granule 0..7
    int wo = (c4 & 1) * 4;       // half-offset within granule

    f32x4 acc[4][4] = {};

    for (int kb = 0; kb < klen / 64; ++kb) {
        int k0 = kbase + kb * 64 + c4 * 4;
        float4 av[8], bv[8];
#pragma unroll
        for (int i = 0; i < 8; ++i) {
            int r = srow + 16 * i;
            av[i] = *(const float4*)&xb[(size_t)(bi * 128 + r) * HW + k0];
            bv[i] = *(const float4*)&xb[(size_t)(bj * 128 + r) * HW + k0];
        }
        __syncthreads();      // previous chunk's MFMA reads done
#pragma unroll
        for (int i = 0; i < 8; ++i) {
            int r = srow + 16 * i;
            int base = r * 64 + ((g ^ (r & 7)) * 8) + wo;
            float af[4] = {av[i].x, av[i].y, av[i].z, av[i].w};
            float bf[4] = {bv[i].x, bv[i].y, bv[i].z, bv[i].w};
            unsigned short ah[4], bhh[4], bll[4];
#pragma unroll
            for (int j = 0; j < 4; ++j) {
                ah[j] = f2bf(af[j]);
                bhh[j] = f2bf(bf[j]);
                bll[j] = f2bf(2.0f * (bf[j] - bf2f(bhh[j])));
            }
            *(uint2*)&Ah[base] = make_uint2((unsigned)ah[0] | ((unsigned)ah[1] << 16),
                                            (unsigned)ah[2] | ((unsigned)ah[3] << 16));
            *(uint2*)&Bh[base] = make_uint2((unsigned)bhh[0] | ((unsigned)bhh[1] << 16),
                                            (unsigned)bhh[2] | ((unsigned)bhh[3] << 16));
            *(uint2*)&Bl[base] = make_uint2((unsigned)bll[0] | ((unsigned)bll[1] << 16),
                                            (unsigned)bll[2] | ((unsigned)bll[3] << 16));
        }
        __syncthreads();      // tiles ready
#pragma unroll
        for (int ks = 0; ks < 2; ++ks) {
            short8 af[4], bhf[4], blf[4];
#pragma unroll
            for (int mi = 0; mi < 4; ++mi) {
                int r = wr + mi * 16 + fr;
                int gk = ks * 4 + fg;
                af[mi] = *(const short8*)&Ah[r * 64 + ((gk ^ (r & 7)) * 8)];
            }
#pragma unroll
            for (int nj = 0; nj < 4; ++nj) {
                int r = wc + nj * 16 + fr;
                int gk = ks * 4 + fg;
                bhf[nj] = *(const short8*)&Bh[r * 64 + ((gk ^ (r & 7)) * 8)];
                blf[nj] = *(const short8*)&Bl[r * 64 + ((gk ^ (r & 7)) * 8)];
            }
#pragma unroll
            for (int mi = 0; mi < 4; ++mi)
#pragma unroll
                for (int nj = 0; nj < 4; ++nj) {
                    acc[mi][nj] = __builtin_amdgcn_mfma_f32_16x16x32_bf16(af[mi], bhf[nj], acc[mi][nj], 0, 0, 0);
                    acc[mi][nj] = __builtin_amdgcn_mfma_f32_16x16x32_bf16(af[mi], blf[nj], acc[mi][nj], 0, 0, 0);
                }
        }
    }

    float* Cp = C1 + ((size_t)(p * BATCH + b)) * CH * CH;
#pragma unroll
    for (int mi = 0; mi < 4; ++mi)
#pragma unroll
        for (int nj = 0; nj < 4; ++nj) {
#pragma unroll
            for (int reg = 0; reg < 4; ++reg) {
                int r = bi * 128 + wr + mi * 16 + fg * 4 + reg;
                int c = bj * 128 + wc + nj * 16 + fr;
                Cp[(size_t)r * CH + c] = acc[mi][nj][reg];
            }
        }
}

// ------- K3: symmetrize + invn weights + batch-quarter sum → cos partials ------
__global__ __launch_bounds__(256) void reduce_cos(const float* __restrict__ C1,
                                                  const float* __restrict__ invn,
                                                  float* __restrict__ cosP,  // [4][256][256]
                                                  int P) {
    int I = blockIdx.x, J = blockIdx.y, q = blockIdx.z;
    __shared__ float Tt[64][65];
    __shared__ float wI[64], wJ[64];
    int t = threadIdx.x;
    int c = t >> 2, d0 = (t & 3) * 16;
    float acc[16] = {};
    for (int b = q * 8; b < q * 8 + 8; ++b) {
        __syncthreads();
        if (t < 64) wI[t] = invn[b * CH + I * 64 + t];
        else if (t < 128) wJ[t - 64] = invn[b * CH + J * 64 + (t - 64)];
        for (int p = 0; p < P; ++p) {
            const float* Cb = C1 + ((size_t)(p * BATCH + b)) * CH * CH;
            float4 t1[4], t2[4];
#pragma unroll
            for (int j4 = 0; j4 < 4; ++j4) {
                t1[j4] = *(const float4*)&Cb[(size_t)(I * 64 + c) * CH + J * 64 + d0 + j4 * 4];
                t2[j4] = *(const float4*)&Cb[(size_t)(J * 64 + c) * CH + I * 64 + d0 + j4 * 4];
            }
            __syncthreads();   // prior Tt reads done; wI/wJ visible
#pragma unroll
            for (int j4 = 0; j4 < 4; ++j4) {
                Tt[c][d0 + j4 * 4 + 0] = t2[j4].x;
                Tt[c][d0 + j4 * 4 + 1] = t2[j4].y;
                Tt[c][d0 + j4 * 4 + 2] = t2[j4].z;
                Tt[c][d0 + j4 * 4 + 3] = t2[j4].w;
            }
            __syncthreads();
            float wcv = wI[c];
            const float* t1f = (const float*)t1;
#pragma unroll
            for (int j = 0; j < 16; ++j) {
                float v = t1f[j] + Tt[d0 + j][c];
                acc[j] += v * wcv * wJ[d0 + j];
            }
        }
    }
    float* op = cosP + (size_t)q * CH * CH;
#pragma unroll
    for (int j4 = 0; j4 < 4; ++j4) {
        float4 o;
        o.x = acc[j4 * 4 + 0]; o.y = acc[j4 * 4 + 1];
        o.z = acc[j4 * 4 + 2]; o.w = acc[j4 * 4 + 3];
        *(float4*)&op[(size_t)(I * 64 + c) * CH + J * 64 + d0 + j4 * 4] = o;
    }
}

// ---------------- K4: top-8 smallest |cos| per column ----------------
__global__ __launch_bounds__(256) void topk_kernel(const float* __restrict__ cosP,
                                                   int* __restrict__ idx) {
    int c = blockIdx.x;
    int d = threadIdx.x;
    float v = 0.f;
#pragma unroll
    for (int q = 0; q < 4; ++q)
        v += cosP[(size_t)q * CH * CH + (size_t)c * CH + d];   // symmetric: row c == col c
    v = fabsf(v * (0.5f / BATCH));

    __shared__ unsigned long long keys[CH];
    __shared__ unsigned long long wmin[4];
    __shared__ unsigned long long bmin;

    keys[d] = ((unsigned long long)__float_as_uint(v) << 32) | (unsigned)d;
    __syncthreads();

    for (int i = 0; i < KSEL; ++i) {
        unsigned long long k = keys[d];
        for (int off = 32; off; off >>= 1) {
            unsigned long long o = __shfl_down(k, off);
            k = (o < k) ? o : k;
        }
        if ((d & 63) == 0) wmin[d >> 6] = k;
        __syncthreads();
        if (d == 0) {
            unsigned long long m = wmin[0];
            if (wmin[1] < m) m = wmin[1];
            if (wmin[2] < m) m = wmin[2];
            if (wmin[3] < m) m = wmin[3];
            bmin = m;
            idx[c * KSEL + i] = (int)(m & 0xffffffffu);
        }
        __syncthreads();
        int sel = (int)(bmin & 0xffffffffu);
        if (d == sel) keys[d] = 0xffffffffffffffffULL;
        __syncthreads();
    }
}

// ---------------- K5: gathered group statistics ----------------
__global__ __launch_bounds__(256) void groupstat_kernel(const float* __restrict__ s,
                                                        const float* __restrict__ sq,
                                                        const int* __restrict__ idx,
                                                        float* __restrict__ mean,
                                                        float* __restrict__ inv) {
    int b = blockIdx.x, c = threadIdx.x;
    float gs = s[b * CH + c], gq = sq[b * CH + c];
#pragma unroll
    for (int i = 1; i < KSEL; ++i) {
        int d = idx[c * KSEL + i];
        gs += s[b * CH + d];
        gq += sq[b * CH + d];
    }
    const float Ninv = 1.0f / (float)(KSEL * HW);
    float m = gs * Ninv;
    float var = gq * Ninv - m * m;
    mean[b * CH + c] = m;
    inv[b * CH + c]  = rsqrtf(var + EPSV);
}

// ---------------- K6: normalize ----------------
__global__ __launch_bounds__(256) void norm_kernel(const float* __restrict__ x,
                                                   const float* __restrict__ mean,
                                                   const float* __restrict__ inv,
                                                   const float* __restrict__ gamma,
                                                   const float* __restrict__ beta,
                                                   float* __restrict__ out) {
    int i = blockIdx.x * 256 + threadIdx.x;
    int bc = i >> 10;
    int c  = bc & (CH - 1);
    float m = mean[bc], v = inv[bc];
    float g  = gamma[c] * v;
    float bt = beta[c] - m * g;
    float4 xv = ((const float4*)x)[i];
    float4 o;
    o.x = xv.x * g + bt;
    o.y = xv.y * g + bt;
    o.z = xv.z * g + bt;
    o.w = xv.w * g + bt;
    ((float4*)out)[i] = o;
}

extern "C" void kernel_launch(void* const* d_in, const int* in_sizes, int n_in,
                              void* d_out, int out_size, void* d_ws, size_t ws_size,
                              hipStream_t stream) {
    const float* x     = (const float*)d_in[0];
    const float* gamma = (const float*)d_in[1];
    const float* beta  = (const float*)d_in[2];
    float* out = (float*)d_out;

    // ws layout (floats)
    size_t need2 = ((size_t)2 * BATCH * CH * CH + 4 * CH * CH + 5 * BATCH * CH + 1024) * 4;
    int P = (ws_size >= need2) ? 2 : 1;

    float* ws   = (float*)d_ws;
    float* C1   = ws;
    float* cosP = C1 + (size_t)P * BATCH * CH * CH;
    float* s    = cosP + 4 * CH * CH;
    float* sq   = s + BATCH * CH;
    float* invn = sq + BATCH * CH;
    float* mean = invn + BATCH * CH;
    float* inv  = mean + BATCH * CH;
    int*   idx  = (int*)(inv + BATCH * CH);

    stats_kernel<<<BATCH * CH, 256, 0, stream>>>(x, s, sq, invn);
    gram_mfma<<<dim3(2, 2, BATCH * P), 256, 0, stream>>>(x, C1, P);
    reduce_cos<<<dim3(4, 4, 4), 256, 0, stream>>>(C1, invn, cosP, P);
    topk_kernel<<<CH, 256, 0, stream>>>(cosP, idx);
    groupstat_kernel<<<BATCH, 256, 0, stream>>>(s, sq, idx, mean, inv);
    norm_kernel<<<(BATCH * CH * HW / 4) / 256, 256, 0, stream>>>(x, mean, inv, gamma, beta, out);
}

// Round 3
// 155.719 us; speedup vs baseline: 2.5898x; 1.4330x over previous
//
#include <hip/hip_runtime.h>
#include <math.h>

#define BATCH 32
#define CH 256
#define HW 4096
#define KSEL 8
#define EPSV 1e-5f

typedef __attribute__((ext_vector_type(8))) short short8;
typedef __attribute__((ext_vector_type(4))) float f32x4;

__device__ __forceinline__ unsigned short f2bf(float f) {
    unsigned u = __float_as_uint(f);
    unsigned r = u + 0x7fffu + ((u >> 16) & 1u);   // RNE
    return (unsigned short)(r >> 16);
}
__device__ __forceinline__ float bf2f(unsigned short h) {
    return __uint_as_float(((unsigned)h) << 16);
}

// ---------------- K1: per-(b,c) spatial sums + inverse norms ----------------
__global__ __launch_bounds__(256) void stats_kernel(const float* __restrict__ x,
                                                    float* __restrict__ s,
                                                    float* __restrict__ sq,
                                                    float* __restrict__ invn) {
    int bc = blockIdx.x;
    const float4* p4 = (const float4*)(x + (size_t)bc * HW);
    int t = threadIdx.x;
    float sum = 0.f, ssq = 0.f;
#pragma unroll
    for (int i = 0; i < 4; ++i) {
        float4 v = p4[t + 256 * i];
        sum += v.x + v.y + v.z + v.w;
        ssq += v.x * v.x + v.y * v.y + v.z * v.z + v.w * v.w;
    }
    for (int off = 32; off; off >>= 1) {
        sum += __shfl_down(sum, off);
        ssq += __shfl_down(ssq, off);
    }
    __shared__ float ls[4], lq[4];
    int wid = t >> 6, lane = t & 63;
    if (lane == 0) { ls[wid] = sum; lq[wid] = ssq; }
    __syncthreads();
    if (t == 0) {
        float S = ls[0] + ls[1] + ls[2] + ls[3];
        float Q = lq[0] + lq[1] + lq[2] + lq[3];
        s[bc] = S;
        sq[bc] = Q;
        invn[bc] = 1.0f / fmaxf(sqrtf(Q), 1e-12f);
    }
}

// ------- K2: normalized-Gram partials: cosP[z] quadrant = Hn*(Hn + 2Ln)^T -------
// A/B rows pre-scaled by invn. 128x128 tile, 4 waves x 64x64 frags, K=HW/Q per
// block, bf16 16x16x32 MFMA, XOR-swizzled LDS granules (validated round 2).
__global__ __launch_bounds__(256, 2) void gram_cos(const float* __restrict__ x,
                                                   const float* __restrict__ invn,
                                                   float* __restrict__ cosP,
                                                   int Q) {
    int bj = blockIdx.x, bi = blockIdx.y;
    int z = blockIdx.z;                 // 0 .. 32*Q-1
    int b = z / Q, q = z - b * Q;
    int klen = HW / Q;
    int kbase = q * klen;
    const float* xb = x + (size_t)b * CH * HW;

    __shared__ unsigned short Ah[128 * 64];
    __shared__ unsigned short Bh[128 * 64];
    __shared__ unsigned short Bl[128 * 64];

    int t = threadIdx.x;
    int lane = t & 63, w = t >> 6;
    int wr = (w >> 1) * 64, wc = (w & 1) * 64;
    int fr = lane & 15, fg = lane >> 4;

    // staging map: thread covers rows srow+16i (i=0..7), float4-col c4
    int srow = t >> 4;       // 0..15
    int c4 = t & 15;         // float col c4*4
    int g = c4 >> 1;         // 16B granule 0..7
    int half = c4 & 1;       // which half of the granule (4 bf16)

    float wA[8], wB[8];
#pragma unroll
    for (int i = 0; i < 8; ++i) {
        wA[i] = invn[b * CH + bi * 128 + srow + 16 * i];
        wB[i] = invn[b * CH + bj * 128 + srow + 16 * i];
    }

    f32x4 acc[4][4] = {};

    for (int kb = 0; kb < klen / 64; ++kb) {
        int k0 = kbase + kb * 64 + c4 * 4;
        float4 av[8], bv[8];
#pragma unroll
        for (int i = 0; i < 8; ++i) {
            int r = srow + 16 * i;
            av[i] = *(const float4*)&xb[(size_t)(bi * 128 + r) * HW + k0];
            bv[i] = *(const float4*)&xb[(size_t)(bj * 128 + r) * HW + k0];
        }
        __syncthreads();          // previous chunk's MFMA reads done
#pragma unroll
        for (int i = 0; i < 8; ++i) {
            int r = srow + 16 * i;
            int base = r * 64 + ((g ^ (r & 7)) * 8) + half * 4;
            float a0 = av[i].x * wA[i], a1 = av[i].y * wA[i];
            float a2 = av[i].z * wA[i], a3 = av[i].w * wA[i];
            float b0 = bv[i].x * wB[i], b1 = bv[i].y * wB[i];
            float b2 = bv[i].z * wB[i], b3 = bv[i].w * wB[i];
            unsigned short ah0 = f2bf(a0), ah1 = f2bf(a1), ah2 = f2bf(a2), ah3 = f2bf(a3);
            unsigned short bh0 = f2bf(b0), bh1 = f2bf(b1), bh2 = f2bf(b2), bh3 = f2bf(b3);
            unsigned short bl0 = f2bf(2.0f * (b0 - bf2f(bh0)));
            unsigned short bl1 = f2bf(2.0f * (b1 - bf2f(bh1)));
            unsigned short bl2 = f2bf(2.0f * (b2 - bf2f(bh2)));
            unsigned short bl3 = f2bf(2.0f * (b3 - bf2f(bh3)));
            *(uint2*)&Ah[base] = make_uint2((unsigned)ah0 | ((unsigned)ah1 << 16),
                                            (unsigned)ah2 | ((unsigned)ah3 << 16));
            *(uint2*)&Bh[base] = make_uint2((unsigned)bh0 | ((unsigned)bh1 << 16),
                                            (unsigned)bh2 | ((unsigned)bh3 << 16));
            *(uint2*)&Bl[base] = make_uint2((unsigned)bl0 | ((unsigned)bl1 << 16),
                                            (unsigned)bl2 | ((unsigned)bl3 << 16));
        }
        __syncthreads();          // tiles ready
#pragma unroll
        for (int ks = 0; ks < 2; ++ks) {
            short8 af[4], bhf[4], blf[4];
#pragma unroll
            for (int mi = 0; mi < 4; ++mi) {
                int r = wr + mi * 16 + fr;
                int gk = ks * 4 + fg;
                af[mi] = *(const short8*)&Ah[r * 64 + ((gk ^ (r & 7)) * 8)];
            }
#pragma unroll
            for (int nj = 0; nj < 4; ++nj) {
                int r = wc + nj * 16 + fr;
                int gk = ks * 4 + fg;
                bhf[nj] = *(const short8*)&Bh[r * 64 + ((gk ^ (r & 7)) * 8)];
                blf[nj] = *(const short8*)&Bl[r * 64 + ((gk ^ (r & 7)) * 8)];
            }
#pragma unroll
            for (int mi = 0; mi < 4; ++mi)
#pragma unroll
                for (int nj = 0; nj < 4; ++nj) {
                    acc[mi][nj] = __builtin_amdgcn_mfma_f32_16x16x32_bf16(af[mi], bhf[nj], acc[mi][nj], 0, 0, 0);
                    acc[mi][nj] = __builtin_amdgcn_mfma_f32_16x16x32_bf16(af[mi], blf[nj], acc[mi][nj], 0, 0, 0);
                }
        }
    }

    float* Cp = cosP + (size_t)z * CH * CH;
#pragma unroll
    for (int mi = 0; mi < 4; ++mi)
#pragma unroll
        for (int nj = 0; nj < 4; ++nj) {
#pragma unroll
            for (int reg = 0; reg < 4; ++reg) {
                int r = bi * 128 + wr + mi * 16 + fg * 4 + reg;
                int c = bj * 128 + wc + nj * 16 + fr;
                Cp[(size_t)r * CH + c] = acc[mi][nj][reg];
            }
        }
}

// ------- K3: sum partials over p-chunk + symmetrize (LDS transpose) -------
__global__ __launch_bounds__(256) void reduce_sym(const float* __restrict__ cosP,
                                                  float* __restrict__ symP,
                                                  int P) {
    int J = blockIdx.x, I = blockIdx.y, zc = blockIdx.z;  // zc 0..7
    int chunk = P >> 3;
    __shared__ float Tt[64][65];
    int t = threadIdx.x;
    int c = t >> 2, d0 = (t & 3) * 16;
    float acc[16] = {};
    for (int p = zc * chunk; p < (zc + 1) * chunk; ++p) {
        const float* Cp = cosP + (size_t)p * CH * CH;
        float4 t1[4], t2[4];
#pragma unroll
        for (int j4 = 0; j4 < 4; ++j4) {
            t1[j4] = *(const float4*)&Cp[(size_t)(I * 64 + c) * CH + J * 64 + d0 + j4 * 4];
            t2[j4] = *(const float4*)&Cp[(size_t)(J * 64 + c) * CH + I * 64 + d0 + j4 * 4];
        }
        __syncthreads();   // prior Tt reads done
#pragma unroll
        for (int j4 = 0; j4 < 4; ++j4) {
            Tt[c][d0 + j4 * 4 + 0] = t2[j4].x;
            Tt[c][d0 + j4 * 4 + 1] = t2[j4].y;
            Tt[c][d0 + j4 * 4 + 2] = t2[j4].z;
            Tt[c][d0 + j4 * 4 + 3] = t2[j4].w;
        }
        __syncthreads();
        const float* t1f = (const float*)t1;
#pragma unroll
        for (int j = 0; j < 16; ++j)
            acc[j] += t1f[j] + Tt[d0 + j][c];
    }
    float* op = symP + (size_t)zc * CH * CH;
#pragma unroll
    for (int j4 = 0; j4 < 4; ++j4) {
        float4 o;
        o.x = acc[j4 * 4 + 0]; o.y = acc[j4 * 4 + 1];
        o.z = acc[j4 * 4 + 2]; o.w = acc[j4 * 4 + 3];
        *(float4*)&op[(size_t)(I * 64 + c) * CH + J * 64 + d0 + j4 * 4] = o;
    }
}

// ---------------- K4: top-8 smallest |cos| per column ----------------
__global__ __launch_bounds__(256) void topk_kernel(const float* __restrict__ symP,
                                                   int* __restrict__ idx) {
    int c = blockIdx.x;
    int d = threadIdx.x;
    float v = 0.f;
#pragma unroll
    for (int zc = 0; zc < 8; ++zc)
        v += symP[(size_t)zc * CH * CH + (size_t)c * CH + d];
    v = fabsf(v * (0.5f / BATCH));

    __shared__ unsigned long long keys[CH];
    __shared__ unsigned long long wmin[4];
    __shared__ unsigned long long bmin;

    keys[d] = ((unsigned long long)__float_as_uint(v) << 32) | (unsigned)d;
    __syncthreads();

    for (int i = 0; i < KSEL; ++i) {
        unsigned long long k = keys[d];
        for (int off = 32; off; off >>= 1) {
            unsigned long long o = __shfl_down(k, off);
            k = (o < k) ? o : k;
        }
        if ((d & 63) == 0) wmin[d >> 6] = k;
        __syncthreads();
        if (d == 0) {
            unsigned long long m = wmin[0];
            if (wmin[1] < m) m = wmin[1];
            if (wmin[2] < m) m = wmin[2];
            if (wmin[3] < m) m = wmin[3];
            bmin = m;
            idx[c * KSEL + i] = (int)(m & 0xffffffffu);
        }
        __syncthreads();
        int sel = (int)(bmin & 0xffffffffu);
        if (d == sel) keys[d] = 0xffffffffffffffffULL;
        __syncthreads();
    }
}

// ---------------- K5: gathered group statistics ----------------
__global__ __launch_bounds__(256) void groupstat_kernel(const float* __restrict__ s,
                                                        const float* __restrict__ sq,
                                                        const int* __restrict__ idx,
                                                        float* __restrict__ mean,
                                                        float* __restrict__ inv) {
    int b = blockIdx.x, c = threadIdx.x;
    float gs = s[b * CH + c], gq = sq[b * CH + c];
#pragma unroll
    for (int i = 1; i < KSEL; ++i) {
        int d = idx[c * KSEL + i];
        gs += s[b * CH + d];
        gq += sq[b * CH + d];
    }
    const float Ninv = 1.0f / (float)(KSEL * HW);
    float m = gs * Ninv;
    float var = gq * Ninv - m * m;
    mean[b * CH + c] = m;
    inv[b * CH + c]  = rsqrtf(var + EPSV);
}

// ---------------- K6: normalize ----------------
__global__ __launch_bounds__(256) void norm_kernel(const float* __restrict__ x,
                                                   const float* __restrict__ mean,
                                                   const float* __restrict__ inv,
                                                   const float* __restrict__ gamma,
                                                   const float* __restrict__ beta,
                                                   float* __restrict__ out) {
    int i = blockIdx.x * 256 + threadIdx.x;
    int bc = i >> 10;
    int c  = bc & (CH - 1);
    float m = mean[bc], v = inv[bc];
    float g  = gamma[c] * v;
    float bt = beta[c] - m * g;
    float4 xv = ((const float4*)x)[i];
    float4 o;
    o.x = xv.x * g + bt;
    o.y = xv.y * g + bt;
    o.z = xv.z * g + bt;
    o.w = xv.w * g + bt;
    ((float4*)out)[i] = o;
}

extern "C" void kernel_launch(void* const* d_in, const int* in_sizes, int n_in,
                              void* d_out, int out_size, void* d_ws, size_t ws_size,
                              hipStream_t stream) {
    const float* x     = (const float*)d_in[0];
    const float* gamma = (const float*)d_in[1];
    const float* beta  = (const float*)d_in[2];
    float* out = (float*)d_out;

    // ws: cosP[32*Q][256][256] + symP[8][256][256] + 5 stat arrays + idx
    size_t small_bytes = ((size_t)8 * CH * CH + 5 * BATCH * CH) * 4 + CH * KSEL * 4;
    int Q = 1;
    if (ws_size >= (size_t)32 * 4 * CH * CH * 4 + small_bytes) Q = 4;
    else if (ws_size >= (size_t)32 * 2 * CH * CH * 4 + small_bytes) Q = 2;
    int P = 32 * Q;

    float* ws   = (float*)d_ws;
    float* cosP = ws;
    float* symP = cosP + (size_t)P * CH * CH;
    float* s    = symP + (size_t)8 * CH * CH;
    float* sq   = s + BATCH * CH;
    float* invn = sq + BATCH * CH;
    float* mean = invn + BATCH * CH;
    float* inv  = mean + BATCH * CH;
    int*   idx  = (int*)(inv + BATCH * CH);

    stats_kernel<<<BATCH * CH, 256, 0, stream>>>(x, s, sq, invn);
    gram_cos<<<dim3(2, 2, P), 256, 0, stream>>>(x, invn, cosP, Q);
    reduce_sym<<<dim3(4, 4, 8), 256, 0, stream>>>(cosP, symP, P);
    topk_kernel<<<CH, 256, 0, stream>>>(symP, idx);
    groupstat_kernel<<<BATCH, 256, 0, stream>>>(s, sq, idx, mean, inv);
    norm_kernel<<<(BATCH * CH * HW / 4) / 256, 256, 0, stream>>>(x, mean, inv, gamma, beta, out);
}